// Round 1
// baseline (282.994 us; speedup 1.0000x reference)
//
#include <hip/hip_runtime.h>
#include <hip/hip_bf16.h>
#include <stdint.h>

// ViewLoRALinear: out[25088,1024] = x@W^T + b + (x@A_v)@B_v, fp32 in/out.
// Prep kernel casts x,W to bf16 (RNE) into d_ws and computes h = x@A_v.
// GEMM: 256x256-tile 8-phase counted-vmcnt schedule (T1+T2+T3+T4+T5 per the
// CDNA4 guide): 512 threads / 8 waves (2Mx4N), BK=64, 128 KiB LDS double
// buffer, chunk-XOR swizzled LDS (0 bank conflicts, measured), staging via
// global_load_lds with pre-swizzled SOURCE addresses, vmcnt never drained to
// 0 in the main loop (vmcnt(4) once per K-tile), setprio(1) around each
// 16-MFMA quadrant cluster, bijective XCD-aware block swizzle (392 % 8 == 0).
//
// Schedule per K-tile kt (4 phases, buffer buf = kt&1):
//   P0: stage A0(kt+1)->buf^1 | ds_read a[mi0-3],b[ni0-1] | BAR lgkm0 | 16 MFMA q(0,0) | BAR
//   P1: stage A1(kt+1)->buf^1 | ds_read b[ni2-3]          | BAR lgkm0 | 16 MFMA q(0,1) | BAR
//   P2: stage B0(kt+2)->buf   | ds_read a[mi4-7]          | BAR lgkm0 | 16 MFMA q(1,1) | BAR
//   P3: stage B1(kt+2)->buf   |                           | BAR | 16 MFMA q(1,0) | vmcnt(4) BAR
// Safety: B reads of tile kt all complete by P1's trailing barrier, so P2/P3
// may overwrite the same-parity B region with kt+2's data. A reads complete
// by P2, and A stages target the other parity. vmcnt(4) at P3 leaves exactly
// B0,B1(kt+2) (2 halves = 4 VMEM insts) in flight => tile kt+1 fully landed.
#define M_TOT 25088
#define N_TOT 1024
#define K_TOT 1024
#define NVIEW 11
#define ROWS_PER_VIEW 1568   // 8 frames * 196 tokens per view_idx entry

// fallback (CONV) tile
#define BM 128
#define BN 128
#define BK 64

#define GRID256 ((M_TOT / 256) * (N_TOT / 256))   // 98*4 = 392
#define CPX256  (GRID256 / 8)                     // 49, exact

typedef unsigned short u16;
typedef __bf16 bf16x8 __attribute__((ext_vector_type(8)));
typedef float f32x4 __attribute__((ext_vector_type(4)));
typedef unsigned short u16x4 __attribute__((ext_vector_type(4)));

// ws layout (fast path): [x_bf16: 25088*1024 u16][W_bf16: 1024*1024 u16][h: 25088*4 f32]
#define XB_ELEMS ((size_t)M_TOT * K_TOT)
#define WB_ELEMS ((size_t)N_TOT * K_TOT)
#define WB_OFF_B (XB_ELEMS * 2)
#define H_OFF_B  (WB_OFF_B + WB_ELEMS * 2)
#define WS_NEEDED (H_OFF_B + (size_t)M_TOT * 4 * 4)

#define BAR()   asm volatile("s_barrier" ::: "memory")
#define LGKM0() asm volatile("s_waitcnt lgkmcnt(0)" ::: "memory")

__device__ __forceinline__ u16 f2bf(float f) {
    union { float f; unsigned int i; } c; c.f = f;
    unsigned int i = c.i;
    return (u16)((i + 0x7FFFu + ((i >> 16) & 1u)) >> 16);  // RNE (finite inputs)
}

// ---------------------------------------------------------------------------
// Kernel 1: prep. Blocks 0..6271: one x-row per wave -> bf16 cast + h[row].
// Blocks 6272..6527: one W-row per wave -> bf16 cast.
// ---------------------------------------------------------------------------
__global__ __launch_bounds__(256) void prep_kernel(
    const float* __restrict__ x, const float* __restrict__ W,
    const int* __restrict__ view_idx, const float* __restrict__ lora_A,
    u16* __restrict__ xb, u16* __restrict__ wb, float* __restrict__ h) {
    const int wave = threadIdx.x >> 6;
    const int lane = threadIdx.x & 63;
    const int blk  = blockIdx.x;

    if (blk >= M_TOT / 4) {  // W cast
        const int row = (blk - M_TOT / 4) * 4 + wave;
        const float* src = W + (size_t)row * K_TOT;
        u16* dst = wb + (size_t)row * K_TOT;
#pragma unroll
        for (int it = 0; it < 4; ++it) {
            const int k = it * 256 + lane * 4;
            float4 v = *(const float4*)(src + k);
            u16x4 o = { f2bf(v.x), f2bf(v.y), f2bf(v.z), f2bf(v.w) };
            *(u16x4*)(dst + k) = o;
        }
        return;
    }

    const int row = blk * 4 + wave;
    int v = view_idx[row / ROWS_PER_VIEW];
    v = v < 0 ? 0 : (v > NVIEW - 1 ? NVIEW - 1 : v);
    const float* A  = lora_A + (size_t)v * (K_TOT * 4);
    const float* xr = x + (size_t)row * K_TOT;
    u16* dst = xb + (size_t)row * K_TOT;

#pragma unroll
    for (int it = 0; it < 4; ++it) {
        const int k = it * 256 + lane * 4;
        float4 xv = *(const float4*)(xr + k);
        u16x4 o = { f2bf(xv.x), f2bf(xv.y), f2bf(xv.z), f2bf(xv.w) };
        *(u16x4*)(dst + k) = o;
    }
    float a0 = 0.f, a1 = 0.f, a2 = 0.f, a3 = 0.f;
#pragma unroll
    for (int it = 0; it < 8; ++it) {
        const int k = it * 128 + lane * 2;
        float2 xv = *(const float2*)(xr + k);
        float4 av0 = *(const float4*)(A + (size_t)k * 4);
        float4 av1 = *(const float4*)(A + (size_t)k * 4 + 4);
        a0 += xv.x * av0.x + xv.y * av1.x;
        a1 += xv.x * av0.y + xv.y * av1.y;
        a2 += xv.x * av0.z + xv.y * av1.z;
        a3 += xv.x * av0.w + xv.y * av1.w;
    }
#pragma unroll
    for (int off = 32; off > 0; off >>= 1) {
        a0 += __shfl_xor(a0, off, 64);
        a1 += __shfl_xor(a1, off, 64);
        a2 += __shfl_xor(a2, off, 64);
        a3 += __shfl_xor(a3, off, 64);
    }
    if (lane == 0)
        *(float4*)(h + (size_t)row * 4) = make_float4(a0, a1, a2, a3);
}

// Fallback h (ws too small): fp32 x, one wave/row.
__global__ __launch_bounds__(256) void h_only_kernel(
    const float* __restrict__ x, const int* __restrict__ view_idx,
    const float* __restrict__ lora_A, float* __restrict__ h) {
    const int row  = blockIdx.x * 4 + (threadIdx.x >> 6);
    const int lane = threadIdx.x & 63;
    int v = view_idx[row / ROWS_PER_VIEW];
    v = v < 0 ? 0 : (v > NVIEW - 1 ? NVIEW - 1 : v);
    const float* A  = lora_A + (size_t)v * (K_TOT * 4);
    const float* xr = x + (size_t)row * K_TOT;
    float a0 = 0.f, a1 = 0.f, a2 = 0.f, a3 = 0.f;
#pragma unroll
    for (int it = 0; it < 8; ++it) {
        const int k = it * 128 + lane * 2;
        float2 xv = *(const float2*)(xr + k);
        float4 av0 = *(const float4*)(A + (size_t)k * 4);
        float4 av1 = *(const float4*)(A + (size_t)k * 4 + 4);
        a0 += xv.x * av0.x + xv.y * av1.x;
        a1 += xv.x * av0.y + xv.y * av1.y;
        a2 += xv.x * av0.z + xv.y * av1.z;
        a3 += xv.x * av0.w + xv.y * av1.w;
    }
#pragma unroll
    for (int off = 32; off > 0; off >>= 1) {
        a0 += __shfl_xor(a0, off, 64);
        a1 += __shfl_xor(a1, off, 64);
        a2 += __shfl_xor(a2, off, 64);
        a3 += __shfl_xor(a3, off, 64);
    }
    if (lane == 0)
        *(float4*)(h + (size_t)row * 4) = make_float4(a0, a1, a2, a3);
}

// ---------------------------------------------------------------------------
// 8-phase 256x256 GEMM helpers
// ---------------------------------------------------------------------------
__device__ __forceinline__ void stage_half(const u16* __restrict__ gpanel,
                                           u16* lhalf, int kofs, int tid) {
    // half = 128 rows x 64 cols bf16 = 16 KB; 512 thr x 16 B x 2 sweeps.
    // LDS dst is linear (lane*16B); XOR swizzle applied to the SOURCE chunk.
#pragma unroll
    for (int ld = 0; ld < 2; ++ld) {
        const int r = ld * 64 + (tid >> 3);
        const int c = ((tid & 7) ^ (r & 7)) << 3;
        __builtin_amdgcn_global_load_lds(
            (const __attribute__((address_space(1))) void*)(gpanel + (size_t)r * K_TOT + kofs + c),
            (__attribute__((address_space(3))) void*)(lhalf + ld * 4096 + tid * 8), 16, 0, 0);
    }
}

__device__ __forceinline__ void read_a(bf16x8 (&a)[4][2], const u16* Abuf,
                                       int mi_base, int l16, int quad, int sw) {
#pragma unroll
    for (int mi = 0; mi < 4; ++mi)
#pragma unroll
        for (int kk = 0; kk < 2; ++kk)
            a[mi][kk] = *(const bf16x8*)(const void*)(
                Abuf + ((mi_base + mi) * 16 + l16) * 64 + (((kk * 4 + quad) ^ sw) << 3));
}

__device__ __forceinline__ void read_b2(bf16x8 (&b)[4][2], const u16* Bbuf, int brow0,
                                        int ni_base, int l16, int quad, int sw) {
#pragma unroll
    for (int ni = 0; ni < 2; ++ni)
#pragma unroll
        for (int kk = 0; kk < 2; ++kk)
            b[ni_base + ni][kk] = *(const bf16x8*)(const void*)(
                Bbuf + (brow0 + (ni_base + ni) * 16 + l16) * 64 + (((kk * 4 + quad) ^ sw) << 3));
}

__device__ __forceinline__ void mfma_q(f32x4 (&acc)[8][4], const bf16x8 (&a)[4][2],
                                       const bf16x8 (&b)[4][2], int mi_off, int ni0) {
    __builtin_amdgcn_s_setprio(1);
#pragma unroll
    for (int mi = 0; mi < 4; ++mi)
#pragma unroll
        for (int ni = 0; ni < 2; ++ni)
#pragma unroll
            for (int kk = 0; kk < 2; ++kk)
                acc[mi_off + mi][ni0 + ni] = __builtin_amdgcn_mfma_f32_16x16x32_bf16(
                    a[mi][kk], b[ni0 + ni][kk], acc[mi_off + mi][ni0 + ni], 0, 0, 0);
    __builtin_amdgcn_s_setprio(0);
}

// ---------------------------------------------------------------------------
// Kernel 2 (fast path): 256x256 tile, 8 waves, 8-phase counted-vmcnt.
// ---------------------------------------------------------------------------
__global__ __launch_bounds__(512, 2) void gemm256_kernel(
    const u16* __restrict__ xb, const u16* __restrict__ wb,
    const float* __restrict__ bias, const int* __restrict__ view_idx,
    const float* __restrict__ lora_B, const float* __restrict__ h,
    float* __restrict__ out) {
    __shared__ u16 As[2][2][8192];   // [buf][half][128*64] 64 KB
    __shared__ u16 Bs[2][2][8192];   // 64 KB

    const int tid = threadIdx.x;
    // Bijective XCD swizzle (392 % 8 == 0): xcd = id&7 owns 49 consecutive wgids.
    const int id   = blockIdx.x;
    const int wgid = (id & 7) * CPX256 + (id >> 3);
    const int by   = wgid >> 2;          // 0..97
    const int bx   = wgid & 3;           // 0..3

    const int lane = tid & 63;
    const int wave = tid >> 6;
    const int wg   = wave >> 2;          // A row-group: waves 0-3 rows 0-127, 4-7 rows 128-255
    const int wn   = wave & 3;           // col group: 64 cols each
    const int l16  = lane & 15;
    const int quad = lane >> 4;
    const int sw   = l16 & 7;
    const int bhalf = wn >> 1;
    const int brow0 = (wn & 1) * 64;

    const u16* Apan0 = xb + (size_t)(by * 256) * K_TOT;
    const u16* Apan1 = Apan0 + (size_t)128 * K_TOT;
    const u16* Bpan0 = wb + (size_t)(bx * 256) * K_TOT;
    const u16* Bpan1 = Bpan0 + (size_t)128 * K_TOT;

    f32x4 acc[8][4] = {};

    // Prologue: tile0 (all 4 halves) + tile1 B halves. A(1) staged at kt=0 P0/P1.
    stage_half(Apan0, &As[0][0][0], 0, tid);
    stage_half(Apan1, &As[0][1][0], 0, tid);
    stage_half(Bpan0, &Bs[0][0][0], 0, tid);
    stage_half(Bpan1, &Bs[0][1][0], 0, tid);
    stage_half(Bpan0, &Bs[1][0][0], 64, tid);
    stage_half(Bpan1, &Bs[1][1][0], 64, tid);
    asm volatile("s_waitcnt vmcnt(4)" ::: "memory");   // tile0 landed; B(1) in flight
    BAR();

    bf16x8 a[4][2], b[4][2];

    for (int kt = 0; kt < K_TOT / 64; ++kt) {
        const int buf  = kt & 1;
        const int nbuf = buf ^ 1;
        const u16* Abuf = &As[buf][wg][0];
        const u16* Bbuf = &Bs[buf][bhalf][0];

        // ---- phase 0: stage A0(kt+1); read a[mi0-3], b[ni0-1]; mfma q(0,0)
        if (kt + 1 < 16) stage_half(Apan0, &As[nbuf][0][0], (kt + 1) * 64, tid);
        read_a(a, Abuf, 0, l16, quad, sw);
        read_b2(b, Bbuf, brow0, 0, l16, quad, sw);
        BAR(); LGKM0();
        mfma_q(acc, a, b, 0, 0);
        BAR();

        // ---- phase 1: stage A1(kt+1); read b[ni2-3]; mfma q(0,1)
        if (kt + 1 < 16) stage_half(Apan1, &As[nbuf][1][0], (kt + 1) * 64, tid);
        read_b2(b, Bbuf, brow0, 2, l16, quad, sw);
        BAR(); LGKM0();
        mfma_q(acc, a, b, 0, 2);
        BAR();

        // ---- phase 2: stage B0(kt+2) (region dead since P1 barrier); read a[mi4-7]; mfma q(1,1)
        if (kt + 2 < 16) stage_half(Bpan0, &Bs[buf][0][0], (kt + 2) * 64, tid);
        read_a(a, Abuf, 4, l16, quad, sw);
        BAR(); LGKM0();
        mfma_q(acc, a, b, 4, 2);
        BAR();

        // ---- phase 3: stage B1(kt+2); mfma q(1,0); counted vmcnt; barrier
        if (kt + 2 < 16) stage_half(Bpan1, &Bs[buf][1][0], (kt + 2) * 64, tid);
        BAR();
        mfma_q(acc, a, b, 4, 0);
        if (kt < 14) { asm volatile("s_waitcnt vmcnt(4)" ::: "memory"); }
        else         { asm volatile("s_waitcnt vmcnt(0)" ::: "memory"); }
        BAR();
    }

    // Epilogue. C/D layout (m89): col = lane&15, row = quad*4 + reg.
    const int rowBase = by * 256 + wg * 128;
    const int colBase = bx * 256 + wn * 64;
    float biasv[4];
#pragma unroll
    for (int ni = 0; ni < 4; ++ni) biasv[ni] = bias[colBase + ni * 16 + l16];

    const int ve0 = (by * 256) / ROWS_PER_VIEW;
    const int ve1 = (by * 256 + 255) / ROWS_PER_VIEW;
    if (ve0 == ve1) {
        int v = view_idx[ve0];
        v = v < 0 ? 0 : (v > NVIEW - 1 ? NVIEW - 1 : v);
        const float* Bv = lora_B + (size_t)v * (4 * N_TOT);
        float Bvv[4][4];
#pragma unroll
        for (int r = 0; r < 4; ++r)
#pragma unroll
            for (int ni = 0; ni < 4; ++ni)
                Bvv[r][ni] = Bv[r * N_TOT + colBase + ni * 16 + l16];
#pragma unroll
        for (int mi = 0; mi < 8; ++mi) {
#pragma unroll
            for (int reg = 0; reg < 4; ++reg) {
                const int grow = rowBase + mi * 16 + quad * 4 + reg;
                const float4 hv = *(const float4*)(h + (size_t)grow * 4);
                float* orow = out + (size_t)grow * N_TOT;
#pragma unroll
                for (int ni = 0; ni < 4; ++ni) {
                    float lora = hv.x * Bvv[0][ni] + hv.y * Bvv[1][ni]
                               + hv.z * Bvv[2][ni] + hv.w * Bvv[3][ni];
                    orow[colBase + ni * 16 + l16] = acc[mi][ni][reg] + biasv[ni] + lora;
                }
            }
        }
    } else {
#pragma unroll
        for (int mi = 0; mi < 8; ++mi) {
#pragma unroll
            for (int reg = 0; reg < 4; ++reg) {
                const int grow = rowBase + mi * 16 + quad * 4 + reg;
                int v = view_idx[grow / ROWS_PER_VIEW];
                v = v < 0 ? 0 : (v > NVIEW - 1 ? NVIEW - 1 : v);
                const float4 hv = *(const float4*)(h + (size_t)grow * 4);
                const float* Bv = lora_B + (size_t)v * (4 * N_TOT);
                float* orow = out + (size_t)grow * N_TOT;
#pragma unroll
                for (int ni = 0; ni < 4; ++ni) {
                    const int gcol = colBase + ni * 16 + l16;
                    float lora = hv.x * Bv[gcol]
                               + hv.y * Bv[N_TOT + gcol]
                               + hv.z * Bv[2 * N_TOT + gcol]
                               + hv.w * Bv[3 * N_TOT + gcol];
                    orow[gcol] = acc[mi][ni][reg] + biasv[ni] + lora;
                }
            }
        }
    }
}

// ---------------------------------------------------------------------------
// Fallback GEMM (ws too small): 128x128 m97-structure with in-kernel bf16 cast.
// ---------------------------------------------------------------------------
__global__ __launch_bounds__(256) void gemm_conv_kernel(
    const float* __restrict__ xp, const float* __restrict__ Wp,
    const float* __restrict__ bias, const int* __restrict__ view_idx,
    const float* __restrict__ lora_B, const float* __restrict__ h,
    float* __restrict__ out) {
    __shared__ u16 As[BM * BK];
    __shared__ u16 Bs[BN * BK];

    const int tid = threadIdx.x;
    const int id = blockIdx.x;
    int bx, by;
    if (id < 1536) { const int c = id >> 6, w = id & 63; by = c * 8 + (w & 7); bx = w >> 3; }
    else           { const int r = id - 1536; by = 192 + (r & 3); bx = r >> 2; }

    const int lane = tid & 63;
    const int wave = tid >> 6;
    const int wm   = (wave >> 1) * 64;
    const int wn   = (wave & 1) * 64;
    const int l16  = lane & 15;
    const int quad = lane >> 4;
    const int sw   = l16 & 7;

    const size_t a_base = (size_t)(by * BM) * K_TOT;
    const size_t b_base = (size_t)(bx * BN) * K_TOT;

    f32x4 acc[4][4] = {};

    for (int kt = 0; kt < K_TOT / BK; ++kt) {
        const int kofs = kt * BK;
#pragma unroll
        for (int i = 0; i < 8; ++i) {
            const int e = i * 1024 + tid * 4;
            const int r = e >> 6, o = e & 63;
            const int d = r * 64 + (((o >> 3) ^ (r & 7)) << 3) + (o & 7);
            float4 av = *(const float4*)(xp + a_base + (size_t)r * K_TOT + kofs + o);
            float4 bv = *(const float4*)(Wp + b_base + (size_t)r * K_TOT + kofs + o);
            u16x4 ao = { f2bf(av.x), f2bf(av.y), f2bf(av.z), f2bf(av.w) };
            u16x4 bo = { f2bf(bv.x), f2bf(bv.y), f2bf(bv.z), f2bf(bv.w) };
            *(u16x4*)(As + d) = ao;
            *(u16x4*)(Bs + d) = bo;
        }
        __syncthreads();
#pragma unroll
        for (int kk = 0; kk < 2; ++kk) {
            const int csw = (((kk * 4 + quad) ^ sw) << 3);
            bf16x8 a_frag[4], b_frag[4];
#pragma unroll
            for (int mi = 0; mi < 4; ++mi)
                a_frag[mi] = *(const bf16x8*)(const void*)(As + (wm + mi * 16 + l16) * BK + csw);
#pragma unroll
            for (int ni = 0; ni < 4; ++ni)
                b_frag[ni] = *(const bf16x8*)(const void*)(Bs + (wn + ni * 16 + l16) * BK + csw);
#pragma unroll
            for (int mi = 0; mi < 4; ++mi)
#pragma unroll
                for (int ni = 0; ni < 4; ++ni)
                    acc[mi][ni] = __builtin_amdgcn_mfma_f32_16x16x32_bf16(
                        a_frag[mi], b_frag[ni], acc[mi][ni], 0, 0, 0);
        }
        __syncthreads();
    }

    const int rowBase = by * BM + wm;
    const int colBase = bx * BN + wn;
    float biasv[4];
#pragma unroll
    for (int ni = 0; ni < 4; ++ni) biasv[ni] = bias[colBase + ni * 16 + l16];
#pragma unroll
    for (int mi = 0; mi < 4; ++mi) {
#pragma unroll
        for (int reg = 0; reg < 4; ++reg) {
            const int grow = rowBase + mi * 16 + quad * 4 + reg;
            int v = view_idx[grow / ROWS_PER_VIEW];
            v = v < 0 ? 0 : (v > NVIEW - 1 ? NVIEW - 1 : v);
            const float4 hv = *(const float4*)(h + (size_t)grow * 4);
            const float* Bv = lora_B + (size_t)v * (4 * N_TOT);
            float* orow = out + (size_t)grow * N_TOT;
#pragma unroll
            for (int ni = 0; ni < 4; ++ni) {
                const int gcol = colBase + ni * 16 + l16;
                float lora = hv.x * Bv[gcol]
                           + hv.y * Bv[N_TOT + gcol]
                           + hv.z * Bv[2 * N_TOT + gcol]
                           + hv.w * Bv[3 * N_TOT + gcol];
                orow[gcol] = acc[mi][ni][reg] + biasv[ni] + lora;
            }
        }
    }
}

extern "C" void kernel_launch(void* const* d_in, const int* in_sizes, int n_in,
                              void* d_out, int out_size, void* d_ws, size_t ws_size,
                              hipStream_t stream) {
    const float* x        = (const float*)d_in[0];
    const int*   view_idx = (const int*)d_in[1];
    const float* W        = (const float*)d_in[2];
    const float* b        = (const float*)d_in[3];
    const float* lora_A   = (const float*)d_in[4];
    const float* lora_B   = (const float*)d_in[5];
    float* out = (float*)d_out;

    if (ws_size >= WS_NEEDED) {
        u16*   xb = (u16*)d_ws;
        u16*   wb = (u16*)((char*)d_ws + WB_OFF_B);
        float* h  = (float*)((char*)d_ws + H_OFF_B);
        hipLaunchKernelGGL(prep_kernel, dim3(M_TOT / 4 + N_TOT / 4), dim3(256), 0, stream,
                           x, W, view_idx, lora_A, xb, wb, h);
        hipLaunchKernelGGL(gemm256_kernel, dim3(GRID256), dim3(512), 0, stream,
                           xb, wb, b, view_idx, lora_B, h, out);
    } else {
        float* h = (float*)d_ws;  // 401,408 B
        hipLaunchKernelGGL(h_only_kernel, dim3(M_TOT / 4), dim3(256), 0, stream,
                           x, view_idx, lora_A, h);
        hipLaunchKernelGGL(gemm_conv_kernel, dim3((M_TOT / BM) * (N_TOT / BN)), dim3(256), 0, stream,
                           x, W, b, view_idx, lora_B, h, out);
    }
}

// Round 2
// 280.643 us; speedup vs baseline: 1.0084x; 1.0084x over previous
//
#include <hip/hip_runtime.h>
#include <hip/hip_bf16.h>
#include <stdint.h>

// ViewLoRALinear: out[25088,1024] = x@W^T + b + (x@A_v)@B_v, fp32 in/out.
// Prep kernel casts x,W to bf16 (RNE) into d_ws and computes h = x@A_v
// (single fused pass over x). GEMM: 256x256-tile 8-phase counted-vmcnt
// schedule. CRITICAL primitive choice (round-1 lesson): barriers are
// __builtin_amdgcn_s_barrier() and waitcnts are clobber-free inline asm +
// sched_barrier(0). An asm "memory" clobber makes the backend insert
// s_waitcnt vmcnt(0) before the asm while global_load_lds ops are in
// flight, draining the pipeline at every barrier (8x/K-tile) -> that was
// round-1's 128us regression.
//
// Schedule per K-tile kt (4 phases, buffer buf = kt&1):
//   P0: stage A0(kt+1)->buf^1 | ds_read a[mi0-3],b[ni0-1] | BAR lgkm0 | 16 MFMA q(0,0) | BAR
//   P1: stage A1(kt+1)->buf^1 | ds_read b[ni2-3]          | BAR lgkm0 | 16 MFMA q(0,1) | BAR
//   P2: stage B0(kt+2)->buf   | ds_read a[mi4-7]          | BAR lgkm0 | 16 MFMA q(1,1) | BAR
//   P3: stage B1(kt+2)->buf   |                           | BAR | 16 MFMA q(1,0) | vmcnt(4) BAR
// Safety: all Bs[buf] frag reads complete before each wave's P1 MFMA
// (compiler lgkmcnt) hence before P1's trailing barrier -> P2 may overwrite
// Bs[buf] with kt+2 data. Each wave waits vmcnt(4) before P3's trailing
// barrier, so once ALL waves pass it, every wave's A(kt+1) loads have
// landed (B(kt+2)'s 4 loads per thread remain in flight).
#define M_TOT 25088
#define N_TOT 1024
#define K_TOT 1024
#define NVIEW 11
#define ROWS_PER_VIEW 1568   // 8 frames * 196 tokens per view_idx entry

// fallback (CONV) tile
#define BM 128
#define BN 128
#define BK 64

#define GRID256 ((M_TOT / 256) * (N_TOT / 256))   // 98*4 = 392
#define CPX256  (GRID256 / 8)                     // 49, exact

typedef unsigned short u16;
typedef __bf16 bf16x8 __attribute__((ext_vector_type(8)));
typedef float f32x4 __attribute__((ext_vector_type(4)));
typedef unsigned short u16x4 __attribute__((ext_vector_type(4)));

// ws layout (fast path): [x_bf16: 25088*1024 u16][W_bf16: 1024*1024 u16][h: 25088*4 f32]
#define XB_ELEMS ((size_t)M_TOT * K_TOT)
#define WB_ELEMS ((size_t)N_TOT * K_TOT)
#define WB_OFF_B (XB_ELEMS * 2)
#define H_OFF_B  (WB_OFF_B + WB_ELEMS * 2)
#define WS_NEEDED (H_OFF_B + (size_t)M_TOT * 4 * 4)

#define BAR() __builtin_amdgcn_s_barrier()
#define LGKM0_FENCE() do { asm volatile("s_waitcnt lgkmcnt(0)"); \
                           __builtin_amdgcn_sched_barrier(0); } while (0)
#define VMCNT4_FENCE() do { asm volatile("s_waitcnt vmcnt(4)"); \
                            __builtin_amdgcn_sched_barrier(0); } while (0)
#define VMCNT0_FENCE() do { asm volatile("s_waitcnt vmcnt(0)"); \
                            __builtin_amdgcn_sched_barrier(0); } while (0)

__device__ __forceinline__ u16 f2bf(float f) {
    union { float f; unsigned int i; } c; c.f = f;
    unsigned int i = c.i;
    return (u16)((i + 0x7FFFu + ((i >> 16) & 1u)) >> 16);  // RNE (finite inputs)
}

// ---------------------------------------------------------------------------
// Kernel 1: prep. Blocks 0..6271: one x-row per wave -> bf16 cast + h[row]
// in a SINGLE fused pass (h accumulated from the same float4 as the cast;
// removes the second x read of the previous version). Blocks 6272..6527:
// one W-row per wave -> bf16 cast.
// ---------------------------------------------------------------------------
__global__ __launch_bounds__(256) void prep_kernel(
    const float* __restrict__ x, const float* __restrict__ W,
    const int* __restrict__ view_idx, const float* __restrict__ lora_A,
    u16* __restrict__ xb, u16* __restrict__ wb, float* __restrict__ h) {
    const int wave = threadIdx.x >> 6;
    const int lane = threadIdx.x & 63;
    const int blk  = blockIdx.x;

    if (blk >= M_TOT / 4) {  // W cast
        const int row = (blk - M_TOT / 4) * 4 + wave;
        const float* src = W + (size_t)row * K_TOT;
        u16* dst = wb + (size_t)row * K_TOT;
#pragma unroll
        for (int it = 0; it < 4; ++it) {
            const int k = it * 256 + lane * 4;
            float4 v = *(const float4*)(src + k);
            u16x4 o = { f2bf(v.x), f2bf(v.y), f2bf(v.z), f2bf(v.w) };
            *(u16x4*)(dst + k) = o;
        }
        return;
    }

    const int row = blk * 4 + wave;
    int v = view_idx[row / ROWS_PER_VIEW];
    v = v < 0 ? 0 : (v > NVIEW - 1 ? NVIEW - 1 : v);
    const float* A  = lora_A + (size_t)v * (K_TOT * 4);  // [K][4] row-major
    const float* xr = x + (size_t)row * K_TOT;
    u16* dst = xb + (size_t)row * K_TOT;

    float a0 = 0.f, a1 = 0.f, a2 = 0.f, a3 = 0.f;
#pragma unroll
    for (int it = 0; it < 4; ++it) {
        const int k = it * 256 + lane * 4;
        float4 xv = *(const float4*)(xr + k);
        u16x4 o = { f2bf(xv.x), f2bf(xv.y), f2bf(xv.z), f2bf(xv.w) };
        *(u16x4*)(dst + k) = o;
        float4 av0 = *(const float4*)(A + (size_t)(k + 0) * 4);
        float4 av1 = *(const float4*)(A + (size_t)(k + 1) * 4);
        float4 av2 = *(const float4*)(A + (size_t)(k + 2) * 4);
        float4 av3 = *(const float4*)(A + (size_t)(k + 3) * 4);
        a0 += xv.x * av0.x + xv.y * av1.x + xv.z * av2.x + xv.w * av3.x;
        a1 += xv.x * av0.y + xv.y * av1.y + xv.z * av2.y + xv.w * av3.y;
        a2 += xv.x * av0.z + xv.y * av1.z + xv.z * av2.z + xv.w * av3.z;
        a3 += xv.x * av0.w + xv.y * av1.w + xv.z * av2.w + xv.w * av3.w;
    }
#pragma unroll
    for (int off = 32; off > 0; off >>= 1) {
        a0 += __shfl_xor(a0, off, 64);
        a1 += __shfl_xor(a1, off, 64);
        a2 += __shfl_xor(a2, off, 64);
        a3 += __shfl_xor(a3, off, 64);
    }
    if (lane == 0)
        *(float4*)(h + (size_t)row * 4) = make_float4(a0, a1, a2, a3);
}

// Fallback h (ws too small): fp32 x, one wave/row.
__global__ __launch_bounds__(256) void h_only_kernel(
    const float* __restrict__ x, const int* __restrict__ view_idx,
    const float* __restrict__ lora_A, float* __restrict__ h) {
    const int row  = blockIdx.x * 4 + (threadIdx.x >> 6);
    const int lane = threadIdx.x & 63;
    int v = view_idx[row / ROWS_PER_VIEW];
    v = v < 0 ? 0 : (v > NVIEW - 1 ? NVIEW - 1 : v);
    const float* A  = lora_A + (size_t)v * (K_TOT * 4);
    const float* xr = x + (size_t)row * K_TOT;
    float a0 = 0.f, a1 = 0.f, a2 = 0.f, a3 = 0.f;
#pragma unroll
    for (int it = 0; it < 4; ++it) {
        const int k = it * 256 + lane * 4;
        float4 xv = *(const float4*)(xr + k);
        float4 av0 = *(const float4*)(A + (size_t)(k + 0) * 4);
        float4 av1 = *(const float4*)(A + (size_t)(k + 1) * 4);
        float4 av2 = *(const float4*)(A + (size_t)(k + 2) * 4);
        float4 av3 = *(const float4*)(A + (size_t)(k + 3) * 4);
        a0 += xv.x * av0.x + xv.y * av1.x + xv.z * av2.x + xv.w * av3.x;
        a1 += xv.x * av0.y + xv.y * av1.y + xv.z * av2.y + xv.w * av3.y;
        a2 += xv.x * av0.z + xv.y * av1.z + xv.z * av2.z + xv.w * av3.z;
        a3 += xv.x * av0.w + xv.y * av1.w + xv.z * av2.w + xv.w * av3.w;
    }
#pragma unroll
    for (int off = 32; off > 0; off >>= 1) {
        a0 += __shfl_xor(a0, off, 64);
        a1 += __shfl_xor(a1, off, 64);
        a2 += __shfl_xor(a2, off, 64);
        a3 += __shfl_xor(a3, off, 64);
    }
    if (lane == 0)
        *(float4*)(h + (size_t)row * 4) = make_float4(a0, a1, a2, a3);
}

// ---------------------------------------------------------------------------
// 8-phase 256x256 GEMM helpers
// ---------------------------------------------------------------------------
__device__ __forceinline__ void stage_half(const u16* __restrict__ gpanel,
                                           u16* lhalf, int kofs, int tid) {
    // half = 128 rows x 64 cols bf16 = 16 KB; 512 thr x 16 B x 2 sweeps.
    // LDS dst is linear (lane*16B); XOR swizzle applied to the SOURCE chunk.
#pragma unroll
    for (int ld = 0; ld < 2; ++ld) {
        const int r = ld * 64 + (tid >> 3);
        const int c = ((tid & 7) ^ (r & 7)) << 3;
        __builtin_amdgcn_global_load_lds(
            (const __attribute__((address_space(1))) void*)(gpanel + (size_t)r * K_TOT + kofs + c),
            (__attribute__((address_space(3))) void*)(lhalf + ld * 4096 + tid * 8), 16, 0, 0);
    }
}

__device__ __forceinline__ void read_a(bf16x8 (&a)[4][2], const u16* Abuf,
                                       int mi_base, int l16, int quad, int sw) {
#pragma unroll
    for (int mi = 0; mi < 4; ++mi)
#pragma unroll
        for (int kk = 0; kk < 2; ++kk)
            a[mi][kk] = *(const bf16x8*)(const void*)(
                Abuf + ((mi_base + mi) * 16 + l16) * 64 + (((kk * 4 + quad) ^ sw) << 3));
}

__device__ __forceinline__ void read_b2(bf16x8 (&b)[4][2], const u16* Bbuf, int brow0,
                                        int ni_base, int l16, int quad, int sw) {
#pragma unroll
    for (int ni = 0; ni < 2; ++ni)
#pragma unroll
        for (int kk = 0; kk < 2; ++kk)
            b[ni_base + ni][kk] = *(const bf16x8*)(const void*)(
                Bbuf + (brow0 + (ni_base + ni) * 16 + l16) * 64 + (((kk * 4 + quad) ^ sw) << 3));
}

__device__ __forceinline__ void mfma_q(f32x4 (&acc)[8][4], const bf16x8 (&a)[4][2],
                                       const bf16x8 (&b)[4][2], int mi_off, int ni0) {
    __builtin_amdgcn_s_setprio(1);
#pragma unroll
    for (int mi = 0; mi < 4; ++mi)
#pragma unroll
        for (int ni = 0; ni < 2; ++ni)
#pragma unroll
            for (int kk = 0; kk < 2; ++kk)
                acc[mi_off + mi][ni0 + ni] = __builtin_amdgcn_mfma_f32_16x16x32_bf16(
                    a[mi][kk], b[ni0 + ni][kk], acc[mi_off + mi][ni0 + ni], 0, 0, 0);
    __builtin_amdgcn_s_setprio(0);
}

// ---------------------------------------------------------------------------
// Kernel 2 (fast path): 256x256 tile, 8 waves, 8-phase counted-vmcnt.
// ---------------------------------------------------------------------------
__global__ __launch_bounds__(512, 2) void gemm256_kernel(
    const u16* __restrict__ xb, const u16* __restrict__ wb,
    const float* __restrict__ bias, const int* __restrict__ view_idx,
    const float* __restrict__ lora_B, const float* __restrict__ h,
    float* __restrict__ out) {
    __shared__ u16 As[2][2][8192];   // [buf][half][128*64] 64 KB
    __shared__ u16 Bs[2][2][8192];   // 64 KB

    const int tid = threadIdx.x;
    // Bijective XCD swizzle (392 % 8 == 0): xcd = id&7 owns 49 consecutive wgids.
    const int id   = blockIdx.x;
    const int wgid = (id & 7) * CPX256 + (id >> 3);
    const int by   = wgid >> 2;          // 0..97
    const int bx   = wgid & 3;           // 0..3

    const int lane = tid & 63;
    const int wave = tid >> 6;
    const int wg   = wave >> 2;          // A row-group: waves 0-3 rows 0-127, 4-7 rows 128-255
    const int wn   = wave & 3;           // col group: 64 cols each
    const int l16  = lane & 15;
    const int quad = lane >> 4;
    const int sw   = l16 & 7;
    const int bhalf = wn >> 1;
    const int brow0 = (wn & 1) * 64;

    const u16* Apan0 = xb + (size_t)(by * 256) * K_TOT;
    const u16* Apan1 = Apan0 + (size_t)128 * K_TOT;
    const u16* Bpan0 = wb + (size_t)(bx * 256) * K_TOT;
    const u16* Bpan1 = Bpan0 + (size_t)128 * K_TOT;

    f32x4 acc[8][4] = {};

    // Prologue: tile0 (all 4 halves) + tile1 B halves. A(1) staged at kt=0 P0/P1.
    stage_half(Apan0, &As[0][0][0], 0, tid);
    stage_half(Apan1, &As[0][1][0], 0, tid);
    stage_half(Bpan0, &Bs[0][0][0], 0, tid);
    stage_half(Bpan1, &Bs[0][1][0], 0, tid);
    stage_half(Bpan0, &Bs[1][0][0], 64, tid);
    stage_half(Bpan1, &Bs[1][1][0], 64, tid);
    VMCNT4_FENCE();   // tile0 landed; B(1)'s 4 loads stay in flight
    BAR();

    bf16x8 a[4][2], b[4][2];

    for (int kt = 0; kt < K_TOT / 64; ++kt) {
        const int buf  = kt & 1;
        const int nbuf = buf ^ 1;
        const u16* Abuf = &As[buf][wg][0];
        const u16* Bbuf = &Bs[buf][bhalf][0];

        // ---- phase 0: stage A0(kt+1); read a[mi0-3], b[ni0-1]; mfma q(0,0)
        if (kt + 1 < 16) stage_half(Apan0, &As[nbuf][0][0], (kt + 1) * 64, tid);
        read_a(a, Abuf, 0, l16, quad, sw);
        read_b2(b, Bbuf, brow0, 0, l16, quad, sw);
        BAR(); LGKM0_FENCE();
        mfma_q(acc, a, b, 0, 0);
        BAR();

        // ---- phase 1: stage A1(kt+1); read b[ni2-3]; mfma q(0,1)
        if (kt + 1 < 16) stage_half(Apan1, &As[nbuf][1][0], (kt + 1) * 64, tid);
        read_b2(b, Bbuf, brow0, 2, l16, quad, sw);
        BAR(); LGKM0_FENCE();
        mfma_q(acc, a, b, 0, 2);
        BAR();

        // ---- phase 2: stage B0(kt+2) (region dead since P1 barrier); read a[mi4-7]; mfma q(1,1)
        if (kt + 2 < 16) stage_half(Bpan0, &Bs[buf][0][0], (kt + 2) * 64, tid);
        read_a(a, Abuf, 4, l16, quad, sw);
        BAR(); LGKM0_FENCE();
        mfma_q(acc, a, b, 4, 2);
        BAR();

        // ---- phase 3: stage B1(kt+2); mfma q(1,0); counted vmcnt; barrier
        if (kt + 2 < 16) stage_half(Bpan1, &Bs[buf][1][0], (kt + 2) * 64, tid);
        BAR();
        mfma_q(acc, a, b, 4, 0);
        if (kt < 14) { VMCNT4_FENCE(); }
        else         { VMCNT0_FENCE(); }
        BAR();
    }

    // Epilogue. C/D layout (m89): col = lane&15, row = quad*4 + reg.
    const int rowBase = by * 256 + wg * 128;
    const int colBase = bx * 256 + wn * 64;
    float biasv[4];
#pragma unroll
    for (int ni = 0; ni < 4; ++ni) biasv[ni] = bias[colBase + ni * 16 + l16];

    const int ve0 = (by * 256) / ROWS_PER_VIEW;
    const int ve1 = (by * 256 + 255) / ROWS_PER_VIEW;
    if (ve0 == ve1) {
        int v = view_idx[ve0];
        v = v < 0 ? 0 : (v > NVIEW - 1 ? NVIEW - 1 : v);
        const float* Bv = lora_B + (size_t)v * (4 * N_TOT);
        float Bvv[4][4];
#pragma unroll
        for (int r = 0; r < 4; ++r)
#pragma unroll
            for (int ni = 0; ni < 4; ++ni)
                Bvv[r][ni] = Bv[r * N_TOT + colBase + ni * 16 + l16];
#pragma unroll
        for (int mi = 0; mi < 8; ++mi) {
#pragma unroll
            for (int reg = 0; reg < 4; ++reg) {
                const int grow = rowBase + mi * 16 + quad * 4 + reg;
                const float4 hv = *(const float4*)(h + (size_t)grow * 4);
                float* orow = out + (size_t)grow * N_TOT;
#pragma unroll
                for (int ni = 0; ni < 4; ++ni) {
                    float lora = hv.x * Bvv[0][ni] + hv.y * Bvv[1][ni]
                               + hv.z * Bvv[2][ni] + hv.w * Bvv[3][ni];
                    orow[colBase + ni * 16 + l16] = acc[mi][ni][reg] + biasv[ni] + lora;
                }
            }
        }
    } else {
#pragma unroll
        for (int mi = 0; mi < 8; ++mi) {
#pragma unroll
            for (int reg = 0; reg < 4; ++reg) {
                const int grow = rowBase + mi * 16 + quad * 4 + reg;
                int v = view_idx[grow / ROWS_PER_VIEW];
                v = v < 0 ? 0 : (v > NVIEW - 1 ? NVIEW - 1 : v);
                const float4 hv = *(const float4*)(h + (size_t)grow * 4);
                const float* Bv = lora_B + (size_t)v * (4 * N_TOT);
                float* orow = out + (size_t)grow * N_TOT;
#pragma unroll
                for (int ni = 0; ni < 4; ++ni) {
                    const int gcol = colBase + ni * 16 + l16;
                    float lora = hv.x * Bv[gcol]
                               + hv.y * Bv[N_TOT + gcol]
                               + hv.z * Bv[2 * N_TOT + gcol]
                               + hv.w * Bv[3 * N_TOT + gcol];
                    orow[gcol] = acc[mi][ni][reg] + biasv[ni] + lora;
                }
            }
        }
    }
}

// ---------------------------------------------------------------------------
// Fallback GEMM (ws too small): 128x128 m97-structure with in-kernel bf16 cast.
// ---------------------------------------------------------------------------
__global__ __launch_bounds__(256) void gemm_conv_kernel(
    const float* __restrict__ xp, const float* __restrict__ Wp,
    const float* __restrict__ bias, const int* __restrict__ view_idx,
    const float* __restrict__ lora_B, const float* __restrict__ h,
    float* __restrict__ out) {
    __shared__ u16 As[BM * BK];
    __shared__ u16 Bs[BN * BK];

    const int tid = threadIdx.x;
    const int id = blockIdx.x;
    int bx, by;
    if (id < 1536) { const int c = id >> 6, w = id & 63; by = c * 8 + (w & 7); bx = w >> 3; }
    else           { const int r = id - 1536; by = 192 + (r & 3); bx = r >> 2; }

    const int lane = tid & 63;
    const int wave = tid >> 6;
    const int wm   = (wave >> 1) * 64;
    const int wn   = (wave & 1) * 64;
    const int l16  = lane & 15;
    const int quad = lane >> 4;
    const int sw   = l16 & 7;

    const size_t a_base = (size_t)(by * BM) * K_TOT;
    const size_t b_base = (size_t)(bx * BN) * K_TOT;

    f32x4 acc[4][4] = {};

    for (int kt = 0; kt < K_TOT / BK; ++kt) {
        const int kofs = kt * BK;
#pragma unroll
        for (int i = 0; i < 8; ++i) {
            const int e = i * 1024 + tid * 4;
            const int r = e >> 6, o = e & 63;
            const int d = r * 64 + (((o >> 3) ^ (r & 7)) << 3) + (o & 7);
            float4 av = *(const float4*)(xp + a_base + (size_t)r * K_TOT + kofs + o);
            float4 bv = *(const float4*)(Wp + b_base + (size_t)r * K_TOT + kofs + o);
            u16x4 ao = { f2bf(av.x), f2bf(av.y), f2bf(av.z), f2bf(av.w) };
            u16x4 bo = { f2bf(bv.x), f2bf(bv.y), f2bf(bv.z), f2bf(bv.w) };
            *(u16x4*)(As + d) = ao;
            *(u16x4*)(Bs + d) = bo;
        }
        __syncthreads();
#pragma unroll
        for (int kk = 0; kk < 2; ++kk) {
            const int csw = (((kk * 4 + quad) ^ sw) << 3);
            bf16x8 a_frag[4], b_frag[4];
#pragma unroll
            for (int mi = 0; mi < 4; ++mi)
                a_frag[mi] = *(const bf16x8*)(const void*)(As + (wm + mi * 16 + l16) * BK + csw);
#pragma unroll
            for (int ni = 0; ni < 4; ++ni)
                b_frag[ni] = *(const bf16x8*)(const void*)(Bs + (wn + ni * 16 + l16) * BK + csw);
#pragma unroll
            for (int mi = 0; mi < 4; ++mi)
#pragma unroll
                for (int ni = 0; ni < 4; ++ni)
                    acc[mi][ni] = __builtin_amdgcn_mfma_f32_16x16x32_bf16(
                        a_frag[mi], b_frag[ni], acc[mi][ni], 0, 0, 0);
        }
        __syncthreads();
    }

    const int rowBase = by * BM + wm;
    const int colBase = bx * BN + wn;
    float biasv[4];
#pragma unroll
    for (int ni = 0; ni < 4; ++ni) biasv[ni] = bias[colBase + ni * 16 + l16];
#pragma unroll
    for (int mi = 0; mi < 4; ++mi) {
#pragma unroll
        for (int reg = 0; reg < 4; ++reg) {
            const int grow = rowBase + mi * 16 + quad * 4 + reg;
            int v = view_idx[grow / ROWS_PER_VIEW];
            v = v < 0 ? 0 : (v > NVIEW - 1 ? NVIEW - 1 : v);
            const float4 hv = *(const float4*)(h + (size_t)grow * 4);
            const float* Bv = lora_B + (size_t)v * (4 * N_TOT);
            float* orow = out + (size_t)grow * N_TOT;
#pragma unroll
            for (int ni = 0; ni < 4; ++ni) {
                const int gcol = colBase + ni * 16 + l16;
                float lora = hv.x * Bv[gcol]
                           + hv.y * Bv[N_TOT + gcol]
                           + hv.z * Bv[2 * N_TOT + gcol]
                           + hv.w * Bv[3 * N_TOT + gcol];
                orow[gcol] = acc[mi][ni][reg] + biasv[ni] + lora;
            }
        }
    }
}

extern "C" void kernel_launch(void* const* d_in, const int* in_sizes, int n_in,
                              void* d_out, int out_size, void* d_ws, size_t ws_size,
                              hipStream_t stream) {
    const float* x        = (const float*)d_in[0];
    const int*   view_idx = (const int*)d_in[1];
    const float* W        = (const float*)d_in[2];
    const float* b        = (const float*)d_in[3];
    const float* lora_A   = (const float*)d_in[4];
    const float* lora_B   = (const float*)d_in[5];
    float* out = (float*)d_out;

    if (ws_size >= WS_NEEDED) {
        u16*   xb = (u16*)d_ws;
        u16*   wb = (u16*)((char*)d_ws + WB_OFF_B);
        float* h  = (float*)((char*)d_ws + H_OFF_B);
        hipLaunchKernelGGL(prep_kernel, dim3(M_TOT / 4 + N_TOT / 4), dim3(256), 0, stream,
                           x, W, view_idx, lora_A, xb, wb, h);
        hipLaunchKernelGGL(gemm256_kernel, dim3(GRID256), dim3(512), 0, stream,
                           xb, wb, b, view_idx, lora_B, h, out);
    } else {
        float* h = (float*)d_ws;  // 401,408 B
        hipLaunchKernelGGL(h_only_kernel, dim3(M_TOT / 4), dim3(256), 0, stream,
                           x, view_idx, lora_A, h);
        hipLaunchKernelGGL(gemm_conv_kernel, dim3((M_TOT / BM) * (N_TOT / BN)), dim3(256), 0, stream,
                           x, W, b, view_idx, lora_B, h, out);
    }
}

// Round 3
// 265.130 us; speedup vs baseline: 1.0674x; 1.0585x over previous
//
#include <hip/hip_runtime.h>
#include <hip/hip_bf16.h>
#include <stdint.h>

// ViewLoRALinear: out[25088,1024] = x@W^T + b + (x@A_v)@B_v, fp32 in/out.
// Prep kernel casts x,W to bf16 (RNE) into d_ws and computes h = x@A_v in a
// single fused pass over x. GEMM: round-0 m97-structure 128x128 bf16 MFMA
// kernel (proven 95.4us here) with ONE change: __launch_bounds__(256, 3).
// Rationale (round-2 counters): VGPR_Count excludes AGPRs; 112 VGPR + 64
// AGPR = 176/wave -> 2 waves/SIMD -> 2 blocks/CU, and both tested GEMM
// structures sit at ~25% of both compute and memory roofs (latency-bound,
// Occupancy 17%). 512/3 = 170 regs -> forcing VGPR <= 106 gives 3 blocks/CU
// (12 waves/CU) to fill the per-K-step barrier/drain bubbles via TLP.
// The 256^2 8-phase path is abandoned at this shape: 1 block/CU + 392-block
// grid (77% packing) is structural.
#define M_TOT 25088
#define N_TOT 1024
#define K_TOT 1024
#define NVIEW 11
#define ROWS_PER_VIEW 1568   // 8 frames * 196 tokens per view_idx entry

#define BM 128
#define BN 128
#define BK 64

typedef unsigned short u16;
typedef __bf16 bf16x8 __attribute__((ext_vector_type(8)));
typedef float f32x4 __attribute__((ext_vector_type(4)));
typedef unsigned short u16x4 __attribute__((ext_vector_type(4)));

// ws layout (fast path): [x_bf16: 25088*1024 u16][W_bf16: 1024*1024 u16][h: 25088*4 f32]
#define XB_ELEMS ((size_t)M_TOT * K_TOT)
#define WB_ELEMS ((size_t)N_TOT * K_TOT)
#define WB_OFF_B (XB_ELEMS * 2)
#define H_OFF_B  (WB_OFF_B + WB_ELEMS * 2)
#define WS_NEEDED (H_OFF_B + (size_t)M_TOT * 4 * 4)

__device__ __forceinline__ u16 f2bf(float f) {
    union { float f; unsigned int i; } c; c.f = f;
    unsigned int i = c.i;
    return (u16)((i + 0x7FFFu + ((i >> 16) & 1u)) >> 16);  // RNE (finite inputs)
}

// ---------------------------------------------------------------------------
// Kernel 1: prep. Blocks 0..6271: one x-row per wave -> bf16 cast + h[row]
// in a SINGLE fused pass (h accumulated from the same float4 as the cast).
// Blocks 6272..6527: one W-row per wave -> bf16 cast.
// ---------------------------------------------------------------------------
__global__ __launch_bounds__(256) void prep_kernel(
    const float* __restrict__ x, const float* __restrict__ W,
    const int* __restrict__ view_idx, const float* __restrict__ lora_A,
    u16* __restrict__ xb, u16* __restrict__ wb, float* __restrict__ h) {
    const int wave = threadIdx.x >> 6;
    const int lane = threadIdx.x & 63;
    const int blk  = blockIdx.x;

    if (blk >= M_TOT / 4) {  // W cast
        const int row = (blk - M_TOT / 4) * 4 + wave;
        const float* src = W + (size_t)row * K_TOT;
        u16* dst = wb + (size_t)row * K_TOT;
#pragma unroll
        for (int it = 0; it < 4; ++it) {
            const int k = it * 256 + lane * 4;
            float4 v = *(const float4*)(src + k);
            u16x4 o = { f2bf(v.x), f2bf(v.y), f2bf(v.z), f2bf(v.w) };
            *(u16x4*)(dst + k) = o;
        }
        return;
    }

    const int row = blk * 4 + wave;
    int v = view_idx[row / ROWS_PER_VIEW];
    v = v < 0 ? 0 : (v > NVIEW - 1 ? NVIEW - 1 : v);
    const float* A  = lora_A + (size_t)v * (K_TOT * 4);  // [K][4] row-major
    const float* xr = x + (size_t)row * K_TOT;
    u16* dst = xb + (size_t)row * K_TOT;

    float a0 = 0.f, a1 = 0.f, a2 = 0.f, a3 = 0.f;
#pragma unroll
    for (int it = 0; it < 4; ++it) {
        const int k = it * 256 + lane * 4;
        float4 xv = *(const float4*)(xr + k);
        u16x4 o = { f2bf(xv.x), f2bf(xv.y), f2bf(xv.z), f2bf(xv.w) };
        *(u16x4*)(dst + k) = o;
        float4 av0 = *(const float4*)(A + (size_t)(k + 0) * 4);
        float4 av1 = *(const float4*)(A + (size_t)(k + 1) * 4);
        float4 av2 = *(const float4*)(A + (size_t)(k + 2) * 4);
        float4 av3 = *(const float4*)(A + (size_t)(k + 3) * 4);
        a0 += xv.x * av0.x + xv.y * av1.x + xv.z * av2.x + xv.w * av3.x;
        a1 += xv.x * av0.y + xv.y * av1.y + xv.z * av2.y + xv.w * av3.y;
        a2 += xv.x * av0.z + xv.y * av1.z + xv.z * av2.z + xv.w * av3.z;
        a3 += xv.x * av0.w + xv.y * av1.w + xv.z * av2.w + xv.w * av3.w;
    }
#pragma unroll
    for (int off = 32; off > 0; off >>= 1) {
        a0 += __shfl_xor(a0, off, 64);
        a1 += __shfl_xor(a1, off, 64);
        a2 += __shfl_xor(a2, off, 64);
        a3 += __shfl_xor(a3, off, 64);
    }
    if (lane == 0)
        *(float4*)(h + (size_t)row * 4) = make_float4(a0, a1, a2, a3);
}

// Fallback h (ws too small): fp32 x, one wave/row.
__global__ __launch_bounds__(256) void h_only_kernel(
    const float* __restrict__ x, const int* __restrict__ view_idx,
    const float* __restrict__ lora_A, float* __restrict__ h) {
    const int row  = blockIdx.x * 4 + (threadIdx.x >> 6);
    const int lane = threadIdx.x & 63;
    int v = view_idx[row / ROWS_PER_VIEW];
    v = v < 0 ? 0 : (v > NVIEW - 1 ? NVIEW - 1 : v);
    const float* A  = lora_A + (size_t)v * (K_TOT * 4);
    const float* xr = x + (size_t)row * K_TOT;
    float a0 = 0.f, a1 = 0.f, a2 = 0.f, a3 = 0.f;
#pragma unroll
    for (int it = 0; it < 4; ++it) {
        const int k = it * 256 + lane * 4;
        float4 xv = *(const float4*)(xr + k);
        float4 av0 = *(const float4*)(A + (size_t)(k + 0) * 4);
        float4 av1 = *(const float4*)(A + (size_t)(k + 1) * 4);
        float4 av2 = *(const float4*)(A + (size_t)(k + 2) * 4);
        float4 av3 = *(const float4*)(A + (size_t)(k + 3) * 4);
        a0 += xv.x * av0.x + xv.y * av1.x + xv.z * av2.x + xv.w * av3.x;
        a1 += xv.x * av0.y + xv.y * av1.y + xv.z * av2.y + xv.w * av3.y;
        a2 += xv.x * av0.z + xv.y * av1.z + xv.z * av2.z + xv.w * av3.z;
        a3 += xv.x * av0.w + xv.y * av1.w + xv.z * av2.w + xv.w * av3.w;
    }
#pragma unroll
    for (int off = 32; off > 0; off >>= 1) {
        a0 += __shfl_xor(a0, off, 64);
        a1 += __shfl_xor(a1, off, 64);
        a2 += __shfl_xor(a2, off, 64);
        a3 += __shfl_xor(a3, off, 64);
    }
    if (lane == 0)
        *(float4*)(h + (size_t)row * 4) = make_float4(a0, a1, a2, a3);
}

// ---------------------------------------------------------------------------
// Kernel 2: GEMM C = X*W^T + bias + h*B_v, fp32 out. Round-0 structure.
// LDS layout XOR-swizzled: slot (row r, chunk c) holds global chunk c^(r&7)
// (chunk = 8 elems = 16B). global_load_lds keeps its contiguous lane*16 dst;
// the permutation is applied to the SOURCE address. Fragment ds_read_b128
// applies the same XOR -> 0 measured bank conflicts.
// __launch_bounds__(256, 3): cap VGPR+AGPR at 170/wave -> 3 blocks/CU.
// ---------------------------------------------------------------------------
template <bool CONV>
__global__ __launch_bounds__(256, 3) void gemm_lora_kernel(
    const void* __restrict__ xp, const void* __restrict__ Wp,
    const float* __restrict__ bias, const int* __restrict__ view_idx,
    const float* __restrict__ lora_B, const float* __restrict__ h,
    float* __restrict__ out) {
    __shared__ u16 As[BM * BK];   // 16 KB [BM][BK(swizzled)] bf16
    __shared__ u16 Bs[BN * BK];

    const int tid = threadIdx.x;
    // XCD swizzle: xcd = id%8; XCD x sweeps all 8 bx of by = c*8 + x.
    const int id = blockIdx.x;
    int bx, by;
    if (id < 1536) { const int c = id >> 6, w = id & 63; by = c * 8 + (w & 7); bx = w >> 3; }
    else           { const int r = id - 1536; by = 192 + (r & 3); bx = r >> 2; }

    const int lane = tid & 63;
    const int wave = tid >> 6;
    const int wm   = (wave >> 1) * 64;
    const int wn   = (wave & 1) * 64;
    const int l16  = lane & 15;
    const int quad = lane >> 4;
    const int sw   = l16 & 7;           // fragment-read XOR key

    const size_t a_base = (size_t)(by * BM) * K_TOT;
    const size_t b_base = (size_t)(bx * BN) * K_TOT;

    f32x4 acc[4][4] = {};

    for (int kt = 0; kt < K_TOT / BK; ++kt) {
        const int kofs = kt * BK;
        if constexpr (!CONV) {
            const u16* x = (const u16*)xp;
            const u16* W = (const u16*)Wp;
#pragma unroll
            for (int i = 0; i < 4; ++i) {
                const int e = i * 2048 + tid * 8;          // LDS dst elem (contiguous)
                const int r = e >> 6;                      // tile row
                const int c = (((tid & 7) ^ (r & 7)) << 3); // swizzled SOURCE chunk
                __builtin_amdgcn_global_load_lds(
                    (const __attribute__((address_space(1))) void*)(x + a_base + (size_t)r * K_TOT + kofs + c),
                    (__attribute__((address_space(3))) void*)(As + e), 16, 0, 0);
                __builtin_amdgcn_global_load_lds(
                    (const __attribute__((address_space(1))) void*)(W + b_base + (size_t)r * K_TOT + kofs + c),
                    (__attribute__((address_space(3))) void*)(Bs + e), 16, 0, 0);
            }
        } else {
            const float* x = (const float*)xp;
            const float* W = (const float*)Wp;
#pragma unroll
            for (int i = 0; i < 8; ++i) {
                const int e = i * 1024 + tid * 4;
                const int r = e >> 6, o = e & 63;
                const int d = r * 64 + (((o >> 3) ^ (r & 7)) << 3) + (o & 7); // swizzled dst
                float4 av = *(const float4*)(x + a_base + (size_t)r * K_TOT + kofs + o);
                float4 bv = *(const float4*)(W + b_base + (size_t)r * K_TOT + kofs + o);
                u16x4 ao = { f2bf(av.x), f2bf(av.y), f2bf(av.z), f2bf(av.w) };
                u16x4 bo = { f2bf(bv.x), f2bf(bv.y), f2bf(bv.z), f2bf(bv.w) };
                *(u16x4*)(As + d) = ao;
                *(u16x4*)(Bs + d) = bo;
            }
        }
        __syncthreads();
#pragma unroll
        for (int kk = 0; kk < 2; ++kk) {
            const int csw = (((kk * 4 + quad) ^ sw) << 3);  // swizzled chunk offset
            bf16x8 a_frag[4], b_frag[4];
#pragma unroll
            for (int mi = 0; mi < 4; ++mi)
                a_frag[mi] = *(const bf16x8*)(const void*)(As + (wm + mi * 16 + l16) * BK + csw);
#pragma unroll
            for (int ni = 0; ni < 4; ++ni)
                b_frag[ni] = *(const bf16x8*)(const void*)(Bs + (wn + ni * 16 + l16) * BK + csw);
#pragma unroll
            for (int mi = 0; mi < 4; ++mi)
#pragma unroll
                for (int ni = 0; ni < 4; ++ni)
                    acc[mi][ni] = __builtin_amdgcn_mfma_f32_16x16x32_bf16(
                        a_frag[mi], b_frag[ni], acc[mi][ni], 0, 0, 0);
        }
        __syncthreads();
    }

    // Epilogue. C/D layout (m89): col = lane&15, row = quad*4 + reg.
    const int rowBase = by * BM + wm;
    const int colBase = bx * BN + wn;
    float biasv[4];
#pragma unroll
    for (int ni = 0; ni < 4; ++ni) biasv[ni] = bias[colBase + ni * 16 + l16];

    const int ve0 = (by * BM) / ROWS_PER_VIEW;
    const int ve1 = (by * BM + BM - 1) / ROWS_PER_VIEW;
    if (ve0 == ve1) {
        int v = view_idx[ve0];
        v = v < 0 ? 0 : (v > NVIEW - 1 ? NVIEW - 1 : v);
        const float* Bv = lora_B + (size_t)v * (4 * N_TOT);
        float Bvv[4][4];
#pragma unroll
        for (int r = 0; r < 4; ++r)
#pragma unroll
            for (int ni = 0; ni < 4; ++ni)
                Bvv[r][ni] = Bv[r * N_TOT + colBase + ni * 16 + l16];
#pragma unroll
        for (int mi = 0; mi < 4; ++mi) {
#pragma unroll
            for (int reg = 0; reg < 4; ++reg) {
                const int grow = rowBase + mi * 16 + quad * 4 + reg;
                const float4 hv = *(const float4*)(h + (size_t)grow * 4);
                float* orow = out + (size_t)grow * N_TOT;
#pragma unroll
                for (int ni = 0; ni < 4; ++ni) {
                    float lora = hv.x * Bvv[0][ni] + hv.y * Bvv[1][ni]
                               + hv.z * Bvv[2][ni] + hv.w * Bvv[3][ni];
                    orow[colBase + ni * 16 + l16] = acc[mi][ni][reg] + biasv[ni] + lora;
                }
            }
        }
    } else {
#pragma unroll
        for (int mi = 0; mi < 4; ++mi) {
#pragma unroll
            for (int reg = 0; reg < 4; ++reg) {
                const int grow = rowBase + mi * 16 + quad * 4 + reg;
                int v = view_idx[grow / ROWS_PER_VIEW];
                v = v < 0 ? 0 : (v > NVIEW - 1 ? NVIEW - 1 : v);
                const float4 hv = *(const float4*)(h + (size_t)grow * 4);
                const float* Bv = lora_B + (size_t)v * (4 * N_TOT);
                float* orow = out + (size_t)grow * N_TOT;
#pragma unroll
                for (int ni = 0; ni < 4; ++ni) {
                    const int gcol = colBase + ni * 16 + l16;
                    float lora = hv.x * Bv[gcol]
                               + hv.y * Bv[N_TOT + gcol]
                               + hv.z * Bv[2 * N_TOT + gcol]
                               + hv.w * Bv[3 * N_TOT + gcol];
                    orow[gcol] = acc[mi][ni][reg] + biasv[ni] + lora;
                }
            }
        }
    }
}

extern "C" void kernel_launch(void* const* d_in, const int* in_sizes, int n_in,
                              void* d_out, int out_size, void* d_ws, size_t ws_size,
                              hipStream_t stream) {
    const float* x        = (const float*)d_in[0];
    const int*   view_idx = (const int*)d_in[1];
    const float* W        = (const float*)d_in[2];
    const float* b        = (const float*)d_in[3];
    const float* lora_A   = (const float*)d_in[4];
    const float* lora_B   = (const float*)d_in[5];
    float* out = (float*)d_out;

    const dim3 ggrid((M_TOT / BM) * (N_TOT / BN));  // 1568, swizzled in-kernel
    if (ws_size >= WS_NEEDED) {
        u16*   xb = (u16*)d_ws;
        u16*   wb = (u16*)((char*)d_ws + WB_OFF_B);
        float* h  = (float*)((char*)d_ws + H_OFF_B);
        hipLaunchKernelGGL(prep_kernel, dim3(M_TOT / 4 + N_TOT / 4), dim3(256), 0, stream,
                           x, W, view_idx, lora_A, xb, wb, h);
        hipLaunchKernelGGL((gemm_lora_kernel<false>), ggrid, dim3(256), 0, stream,
                           xb, wb, b, view_idx, lora_B, h, out);
    } else {
        float* h = (float*)d_ws;  // 401,408 B
        hipLaunchKernelGGL(h_only_kernel, dim3(M_TOT / 4), dim3(256), 0, stream,
                           x, view_idx, lora_A, h);
        hipLaunchKernelGGL((gemm_lora_kernel<true>), ggrid, dim3(256), 0, stream,
                           x, W, b, view_idx, lora_B, h, out);
    }
}